// Round 4
// baseline (744.240 us; speedup 1.0000x reference)
//
#include <hip/hip_runtime.h>

// DockBoardAttention: B=65536, NDOCK=3, DCELL=25, C=32, HW=64, HD=16
// R4: occupancy probe. One wave per batch (as R2), but LDS/wave cut 9.8->5.5 KB:
//   - scores computed from g held in REGISTERS (no gT read in score phase)
//   - z-phase transpose through a HALF tile gH[16][64] written twice
//     (c=0..15, z-dots, overwrite with c=16..31, z-dots) -- wave-private LDS is
//     in-order, so the anti-dependency needs no barrier.
// 6 blocks/CU (launch_bounds 256,6) -> 24 waves/CU vs R2's 16.
//
// Algebra: sc[n][s] = sum_c A[n][c] g[c][s],  A = k*(dock@Wq^T + bq)@Wk  (q.bk cancels in softmax)
//          out[n][e] = (sum_c U[e][c] z'[n][c]) / D[n] + c0[e]
//          z'[n][c] = sum_s e[n][s] g[c][s],  e = exp2(sc) (no max-sub: |sc| <~ 2),  D[n] = sum_s e[n][s]
//          U = Wo@Wv, c0 = Wo@bv + bo;  k = 0.25*log2(e) folded into A.
//
// gH swizzle (same layout as R2's verified gT, per 16-row half):
//   value for (channel c, spatial s) at word (r<<6) + 4*((s>>2) ^ r) + (s&3), r = c&15
//   z read: float4 at (r<<6) + ((j ^ r) << 2)  -> retrieves s = 4j..4j+3.

#define NW 4

// ws layout (floats): M[25*32] @0, bkt[32] @800, U[16*32] @832, c0[16] @1344
__global__ void precompute_kernel(const float* __restrict__ Wq, const float* __restrict__ bq,
                                  const float* __restrict__ Wk, const float* __restrict__ Wv,
                                  const float* __restrict__ bv, const float* __restrict__ Wo,
                                  const float* __restrict__ bo, float* __restrict__ ws)
{
    const float K = 0.25f * 1.44269504088896f;
    const int t = threadIdx.x;
    for (int i = t; i < 800; i += 256) {           // M~[j][c] = K * sum_d Wq[d][j]*Wk[d][c]
        int j = i >> 5, c = i & 31;
        float s = 0.f;
        #pragma unroll
        for (int d = 0; d < 16; ++d) s += Wq[d * 25 + j] * Wk[d * 32 + c];
        ws[i] = s * K;
    }
    if (t < 32) {                                   // bkt~[c] = K * sum_d bq[d]*Wk[d][c]
        float s = 0.f;
        #pragma unroll
        for (int d = 0; d < 16; ++d) s += bq[d] * Wk[d * 32 + t];
        ws[800 + t] = s * K;
    }
    for (int i = t; i < 512; i += 256) {            // U[e][c] = sum_d Wo[e][d]*Wv[d][c]
        int e = i >> 5, c = i & 31;
        float s = 0.f;
        #pragma unroll
        for (int d = 0; d < 16; ++d) s += Wo[e * 16 + d] * Wv[d * 32 + c];
        ws[832 + i] = s;
    }
    if (t < 16) {                                   // c0[e] = sum_d Wo[e][d]*bv[d] + bo[e]
        float s = bo[t];
        #pragma unroll
        for (int d = 0; d < 16; ++d) s += Wo[t * 16 + d] * bv[d];
        ws[1344 + t] = s;
    }
}

__device__ __forceinline__ float rl(float v, int srclane) {
    return __int_as_float(__builtin_amdgcn_readlane(__float_as_int(v), srclane));
}

__global__ __launch_bounds__(256, 6) void dock_attn_kernel(
    const float* __restrict__ dock,   // [B,3,25]
    const float* __restrict__ grid,   // [B,32,64]
    const float* __restrict__ ws,     // precomputed M,bkt,U,c0
    float* __restrict__ out,          // [B,48]
    int b_total)
{
    __shared__ __align__(16) float gH[NW][1024];     // swizzled half tile: 16 rows x 64, 4 KB
    __shared__ __align__(16) float AL[NW][96];       // A[n][c], n-major
    __shared__ __align__(16) float attnL[NW][192];   // unnormalized e[n][s]
    __shared__ __align__(16) float zL[NW][104];      // z'[0..95], D[96..98]

    const int tid = threadIdx.x;
    const int w = tid >> 6, lane = tid & 63;
    const int b = blockIdx.x * NW + w;
    if (b >= b_total) return;          // never taken (B%4==0); no barriers so safe

    const float* Mg  = ws;
    const float* bkt = ws + 800;
    const float* Ug  = ws + 832;
    const float* c0  = ws + 1344;

    // ---- g column into regs (lane = spatial s): 32 coalesced 256B loads ----
    const float* gp = grid + (size_t)b * 2048 + lane;
    float g[32];
    #pragma unroll
    for (int c = 0; c < 32; ++c) g[c] = gp[c * 64];

    float d0 = dock[(size_t)b * 75 + lane];                    // dock idx 0..63
    float d1 = (lane < 11) ? dock[(size_t)b * 75 + 64 + lane] : 0.f;  // idx 64..74

    // ---- A[n][c] on lanes 0..31 (c = lane); M read from global (L1-hot) ----
    if (lane < 32) {
        float bi = bkt[lane];
        float a0 = bi, a1 = bi, a2 = bi;
        #pragma unroll
        for (int j = 0; j < 25; ++j) {
            float m = Mg[j * 32 + lane];
            float q0 = rl(d0, j);
            float q1 = rl(d0, 25 + j);
            float q2 = (50 + j < 64) ? rl(d0, 50 + j) : rl(d1, 50 + j - 64);
            a0 = fmaf(q0, m, a0);
            a1 = fmaf(q1, m, a1);
            a2 = fmaf(q2, m, a2);
        }
        AL[w][lane] = a0; AL[w][32 + lane] = a1; AL[w][64 + lane] = a2;
    }

    // ---- scores from g regs + AL broadcast reads ----
    float sc0 = 0.f, sc1 = 0.f, sc2 = 0.f;
    {
        const float4* A4 = (const float4*)&AL[w][0];
        #pragma unroll
        for (int qq = 0; qq < 8; ++qq) {
            float4 a = A4[qq], bb = A4[8 + qq], cc = A4[16 + qq];
            float g0 = g[4 * qq], g1 = g[4 * qq + 1], g2 = g[4 * qq + 2], g3 = g[4 * qq + 3];
            sc0 = fmaf(a.x, g0, fmaf(a.y, g1, fmaf(a.z, g2, fmaf(a.w, g3, sc0))));
            sc1 = fmaf(bb.x, g0, fmaf(bb.y, g1, fmaf(bb.z, g2, fmaf(bb.w, g3, sc1))));
            sc2 = fmaf(cc.x, g0, fmaf(cc.y, g1, fmaf(cc.z, g2, fmaf(cc.w, g3, sc2))));
        }
    }

    // ---- unnormalized numerators (|sc| <~ 2 in exp2 domain -> no max-sub) ----
    attnL[w][lane]       = exp2f(sc0);
    attnL[w][64 + lane]  = exp2f(sc1);
    attnL[w][128 + lane] = exp2f(sc2);

    // ---- transpose half A: channels 0..15 (frees g[0..15]) ----
    #pragma unroll
    for (int c = 0; c < 16; ++c)
        gH[w][(c << 6) + ((((lane >> 2) ^ c) << 2) | (lane & 3))] = g[c];

    // ---- z phase 1: lanes 0..47 -> z[n][c], c=0..15; lanes 48..50 -> D[n] ----
    if (lane < 48) {
        const int n = lane >> 4, r = lane & 15;
        const float4* ar = (const float4*)&attnL[w][n * 64];
        const float* grow = &gH[w][r << 6];
        float ax = 0.f, ay = 0.f, az = 0.f, aw = 0.f;
        #pragma unroll
        for (int j = 0; j < 16; ++j) {
            float4 a  = ar[j];
            float4 gg = *(const float4*)&grow[(j ^ r) << 2];
            ax = fmaf(a.x, gg.x, ax);
            ay = fmaf(a.y, gg.y, ay);
            az = fmaf(a.z, gg.z, az);
            aw = fmaf(a.w, gg.w, aw);
        }
        zL[w][n * 32 + r] = (ax + ay) + (az + aw);
    } else if (lane < 51) {
        const int n = lane - 48;
        const float4* ar = (const float4*)&attnL[w][n * 64];
        float s0 = 0.f, s1 = 0.f, s2 = 0.f, s3 = 0.f;
        #pragma unroll
        for (int j = 0; j < 16; ++j) {
            float4 a = ar[j];
            s0 += a.x; s1 += a.y; s2 += a.z; s3 += a.w;
        }
        zL[w][96 + n] = (s0 + s1) + (s2 + s3);
    }

    // ---- transpose half B: channels 16..31 overwrite rows 0..15
    //      (in-order per-wave LDS: writes cannot pass the phase-1 reads) ----
    #pragma unroll
    for (int c = 16; c < 32; ++c) {
        const int r = c - 16;
        gH[w][(r << 6) + ((((lane >> 2) ^ r) << 2) | (lane & 3))] = g[c];
    }

    // ---- z phase 2: lanes 0..47 -> z[n][c], c=16..31 ----
    if (lane < 48) {
        const int n = lane >> 4, r = lane & 15;
        const float4* ar = (const float4*)&attnL[w][n * 64];
        const float* grow = &gH[w][r << 6];
        float ax = 0.f, ay = 0.f, az = 0.f, aw = 0.f;
        #pragma unroll
        for (int j = 0; j < 16; ++j) {
            float4 a  = ar[j];
            float4 gg = *(const float4*)&grow[(j ^ r) << 2];
            ax = fmaf(a.x, gg.x, ax);
            ay = fmaf(a.y, gg.y, ay);
            az = fmaf(a.z, gg.z, az);
            aw = fmaf(a.w, gg.w, aw);
        }
        zL[w][n * 32 + 16 + r] = (ax + ay) + (az + aw);
    }

    // ---- out[n][e] = (sum_c U[e][c]*z'[n][c]) * (1/D[n]) + c0[e]  (lanes 0..47) ----
    if (lane < 48) {
        const int n = lane >> 4, e = lane & 15;
        const float4* Ur = (const float4*)(Ug + e * 32);
        const float4* zr = (const float4*)&zL[w][n * 32];
        float dinv = __builtin_amdgcn_rcpf(zL[w][96 + n]);
        float acc0 = 0.f, acc1 = 0.f, acc2 = 0.f, acc3 = 0.f;
        #pragma unroll
        for (int qq = 0; qq < 8; ++qq) {
            float4 u = Ur[qq], z = zr[qq];
            acc0 = fmaf(u.x, z.x, acc0);
            acc1 = fmaf(u.y, z.y, acc1);
            acc2 = fmaf(u.z, z.z, acc2);
            acc3 = fmaf(u.w, z.w, acc3);
        }
        out[(size_t)b * 48 + lane] = fmaf((acc0 + acc1) + (acc2 + acc3), dinv, c0[e]);
    }
}

extern "C" void kernel_launch(void* const* d_in, const int* in_sizes, int n_in,
                              void* d_out, int out_size, void* d_ws, size_t ws_size,
                              hipStream_t stream) {
    const float* dock = (const float*)d_in[0];
    const float* grid = (const float*)d_in[1];
    const float* Wq   = (const float*)d_in[2];
    const float* bq   = (const float*)d_in[3];
    const float* Wk   = (const float*)d_in[4];
    // d_in[5] = bk: q.bk is constant over spatial axis -> cancels in softmax; unused
    const float* Wv   = (const float*)d_in[6];
    const float* bv   = (const float*)d_in[7];
    const float* Wo   = (const float*)d_in[8];
    const float* bo   = (const float*)d_in[9];
    float* out = (float*)d_out;
    float* ws  = (float*)d_ws;

    precompute_kernel<<<1, 256, 0, stream>>>(Wq, bq, Wk, Wv, bv, Wo, bo, ws);

    const int b_total = in_sizes[0] / 75;   // 65536
    const int blocks = (b_total + NW - 1) / NW;
    dock_attn_kernel<<<blocks, 256, 0, stream>>>(dock, grid, ws, out, b_total);
}